// Round 17
// baseline (60.646 us; speedup 1.0000x reference)
//
#include <hip/hip_runtime.h>
#include <hip/hip_cooperative_groups.h>
#include <math.h>

#define RR      300   // rois per image
#define NCLS    21    // classes incl background
#define NFG     20    // foreground classes
#define KK      21    // output pad size (== num_classes)
#define THREADS 1024  // 16 waves
#define NWAVES  16

namespace cg = cooperative_groups;

// Block FMA contraction: t = a*b rounded separately, then + c. (bit-exact vs ref, proven R1-R15)
__device__ __forceinline__ float madd_nofma(float a, float b, float c) {
    float t = a * b;
    asm volatile("" : "+v"(t));
    return t + c;
}

// Correctly-rounded float32 exp via double (bit-exact vs ref, proven R1-R15)
__device__ __forceinline__ float exp_acc(float x) {
    return (float)exp((double)x);
}

// pair index for upper-triangle (q <= s2): (0,0..4),(1,1..4),(2,2..4),(3,3..4),(4,4)
__host__ __device__ constexpr int pairidx(int q, int s2) {
    return q * 5 - (q * (q - 1)) / 2 + (s2 - q);
}

// Exact replacement for RN32(inter/U) > 0.3f (U > 0):  (double)inter > M*(double)U,
// M = midpoint(0.3f, nextafterf(0.3f)); products exact in double. (proven R9-R15)
#define M_THR ((((double)0.30000001192092896) + ((double)0.30000004172325134)) * 0.5)

// Cooperative single-dispatch kernel: 160 blocks (one per image,class) run the
// R15 NMS; grid.sync(); blocks 0-7 run the per-image select. 16 waves * 1024thr,
// <=2 blocks/CU on 256 CUs -> co-residency for cooperative launch guaranteed.
__global__ __launch_bounds__(THREADS)
void nms_coop_kernel(const float* __restrict__ cls_prob,   // [B,RR,NCLS]
                     const float* __restrict__ rois,       // [B,RR,5]
                     const float* __restrict__ bbox_pred,  // [B,RR,4*NCLS]
                     const float* __restrict__ im_info,    // [B,3]
                     const float* __restrict__ thr,        // [NCLS]
                     float* __restrict__ wsBoxes,          // [B,NFG,KK,4]
                     unsigned* __restrict__ wsCount,       // [B,NFG]
                     float* __restrict__ out,              // [B,KK,5] then [B] counts
                     int B)
{
    const int blk  = blockIdx.x;
    const int b    = blk & 7;                // XCD-local image (B == 8)
    const int ci   = blk >> 3;               // fg class index 0..19
    const int c    = ci + 1;                 // skip background
    const int lane = threadIdx.x & 63;
    const int wave = threadIdx.x >> 6;

    __shared__ unsigned long long s_keys[RR];     // sortable key per ORIGINAL roi index
    __shared__ unsigned long long s_ckeys[320];   // compacted VALID keys (lim-bounded reads)
    __shared__ unsigned short     s_vpre[RR];     // #valid j < r (exclusive prefix)
    __shared__ unsigned short     s_pr[RR];       // partial rank (upper j-half), waves 5-9
    __shared__ float4 s_boxS[320];                // decoded boxes in SORTED order (+pad)
    __shared__ float  s_areaS[320];
    __shared__ unsigned s_col32[15 * 2 * 64];     // suppression column halves (pre-zeroed)
    __shared__ int s_nv;

    const float imH = im_info[b * 3 + 0];
    const float imW = im_info[b * 3 + 1];
    const float t   = thr[c];

    // ================= Phase A (wave 15) — overlaps decode on waves 0-4 =================
    if (wave == 15) {
        int base = 0;
        #pragma unroll
        for (int s = 0; s < 5; ++s) {
            const int r  = s * 64 + lane;
            const int rc = (r < RR) ? r : 0;
            const float sc = cls_prob[(b * RR + rc) * NCLS + c];
            const bool valid = (r < RR) && (sc > t);
            const unsigned u = valid ? (__float_as_uint(sc) | 0x80000000u) : 0u;
            const unsigned long long key = ((unsigned long long)u << 32) | (unsigned)(~r);
            const unsigned long long m = __ballot(valid);
            const int pre = base + (int)__popcll(m & ((1ull << lane) - 1ull));
            if (r < RR) { s_keys[r] = key; s_vpre[r] = (unsigned short)pre; }
            if (valid)  { s_ckeys[pre] = key; }
            base += (int)__popcll(m);
        }
        if (lane == 0) s_nv = base;
    } else if (wave >= 5) {
        // waves 5-14: zero suppression columns + LDS pads
        for (int idx = (wave - 5) * 64 + lane; idx < 15 * 2 * 64; idx += 10 * 64)
            s_col32[idx] = 0u;
        const int p = (wave - 5) * 64 + lane;
        if (p < 20) { s_boxS[RR + p] = make_float4(0.f, 0.f, 0.f, 0.f); s_areaS[RR + p] = 0.f; }
    }

    // waves 0-4: decode own roi (independent of rank)
    const int  k   = (wave < 5 ? wave : wave - 5) * 60 + lane;  // own roi for wave-pairs
    const bool own = (lane < 60);
    const int  kc  = own ? k : 0;                 // clamped (in-bounds for ALL lanes)
    float dbx1 = 0.f, dby1 = 0.f, dbx2 = 0.f, dby2 = 0.f, darea = 0.f;
    if (wave < 5) {
        const float* rp = &rois[(size_t)(b * RR + kc) * 5];
        const float x1 = rp[1], y1 = rp[2], x2 = rp[3], y2 = rp[4];
        const float4 dv = *(const float4*)&bbox_pred[((size_t)(b * RR + kc) * NCLS + c) * 4];
        // decode (verbatim expressions, proven bit-exact R1-R15)
        float w  = x2 - x1 + 1.0f;
        float h  = y2 - y1 + 1.0f;
        float cx = x1 + 0.5f * w;
        float cy = y1 + 0.5f * h;
        float dx = dv.x * 0.1f;
        float dy = dv.y * 0.1f;
        float dw = dv.z * 0.2f;
        float dh = dv.w * 0.2f;
        float pcx = madd_nofma(dx, w, cx);
        float pcy = madd_nofma(dy, h, cy);
        float pw  = exp_acc(dw) * w;
        float ph  = exp_acc(dh) * h;
        dbx1 = fminf(fmaxf(pcx - 0.5f * pw, 0.0f), imW - 1.0f);
        dby1 = fminf(fmaxf(pcy - 0.5f * ph, 0.0f), imH - 1.0f);
        dbx2 = fminf(fmaxf(pcx + 0.5f * pw, 0.0f), imW - 1.0f);
        dby2 = fminf(fmaxf(pcy + 0.5f * ph, 0.0f), imH - 1.0f);
        darea = (dbx2 - dbx1 + 1.0f) * (dby2 - dby1 + 1.0f);
    }
    __syncthreads();

    const int nv  = s_nv;
    const int nvh = nv >> 1;                      // j-range split point

    // ================= Phase B1: split rank (waves 0-9) =================
    // FULL-EXEC rule (R10/R11 lesson): key loads + readlane loop run at full exec;
    // loads pinned via asm; only stores guarded.
    int   prA = 0;                                // this wave's partial rank
    unsigned long long mykey = 0ull;
    if (wave < 10) {
        unsigned klo[5], khi[5];
        #pragma unroll
        for (int s = 0; s < 5; ++s) {
            const unsigned long long kk2 = s_ckeys[s * 64 + lane];
            klo[s] = (unsigned)kk2;
            khi[s] = (unsigned)(kk2 >> 32);
            asm volatile("" : "+v"(klo[s]), "+v"(khi[s]));   // pin at full exec
        }
        mykey = s_keys[kc];
        const int jlo = (wave >= 5) ? nvh : 0;    // wave-uniform
        const int jhi = (wave >= 5) ? nv  : nvh;
        #pragma unroll
        for (int s = 0; s < 5; ++s) {
            int st = jlo - s * 64; st = (st < 0) ? 0 : st;
            int en = jhi - s * 64; en = (en < 0) ? 0 : ((en > 64) ? 64 : en);
            for (int jj = st; jj < en; ++jj) {
                const unsigned lo = (unsigned)__builtin_amdgcn_readlane((int)klo[s], jj);
                const unsigned hi = (unsigned)__builtin_amdgcn_readlane((int)khi[s], jj);
                const unsigned long long kj = ((unsigned long long)hi << 32) | lo;
                prA += (kj > mykey) ? 1 : 0;
            }
        }
        if (wave >= 5 && own) s_pr[k] = (unsigned short)prA;
    }
    __syncthreads();

    // ================= Phase B2: combine + store (waves 0-4) =================
    if (wave < 5) {
        const int lrank = prA + (int)s_pr[kc];
        const int irank = nv + (k - (int)s_vpre[kc]);         // invalid-roi closed form
        const int rank  = (mykey >> 63) ? lrank : irank;      // branchless select
        if (own) {
            s_boxS[rank]  = make_float4(dbx1, dby1, dbx2, dby2);
            s_areaS[rank] = darea;
        }
    }
    __syncthreads();

    // ================= Phase C: build (all 16 waves, alive tiles only) =================
    const int nb = (nv + 63) >> 6;                 // alive j/i blocks
    const int np = nb * (nb + 1) / 2;              // alive upper-triangle tiles
    const int ntasks = np * 2;                     // 32-row half-tiles
    const double Md = M_THR;
    for (int task = wave; task < ntasks; task += NWAVES) {
        const int pa = task >> 1, h = task & 1;
        int S2 = 0, a = pa;
        while (a > S2) { a -= (S2 + 1); ++S2; }    // S2-major: (0,0),(0,1),(1,1),(0,2)...
        const int Q = a;
        const int qbase = Q * 64;
        int rows = nv - qbase;
        rows = (rows > 64) ? 64 : rows;
        const int rcap = RR - qbase;
        rows = (rows > rcap) ? rcap : rows;
        const int i0 = h * 32;
        int i1 = i0 + 32; i1 = (i1 > rows) ? rows : i1;
        if (i0 >= i1) continue;
        const int jg = S2 * 64 + lane;
        const bool jv = jg < nv;
        const float4 bj = s_boxS[jg];
        const float  aj = s_areaS[jg];
        unsigned colw = 0u;
        #pragma unroll 4
        for (int ii = i0; ii < i1; ++ii) {
            const float4 bi = s_boxS[qbase + ii];   // broadcast (conflict-free)
            const float  ai = s_areaS[qbase + ii];
            float xx1 = fmaxf(bi.x, bj.x);
            float yy1 = fmaxf(bi.y, bj.y);
            float xx2 = fminf(bi.z, bj.z);
            float yy2 = fminf(bi.w, bj.w);
            float inter = fmaxf(xx2 - xx1 + 1.0f, 0.0f) * fmaxf(yy2 - yy1 + 1.0f, 0.0f);
            float uni = (ai + aj) - inter;
            bool sup = ((double)inter > Md * (double)uni);
            bool gtr = (S2 > Q) || (lane > ii);
            colw |= (sup && gtr && jv) ? (1u << (ii - i0)) : 0u;
        }
        s_col32[(pairidx(Q, S2) * 2 + h) * 64 + lane] = colw;
    }
    __syncthreads();

    // ================= Phase D (wave 0 only; NO return — all threads reach grid.sync) =====
    if (wave == 0) {
        float4 bx[5];
        unsigned keep = 0;
        #pragma unroll
        for (int s = 0; s < 5; ++s) {
            bx[s] = s_boxS[s * 64 + lane];
            keep |= (((s * 64 + lane) < nv) ? 1u : 0u) << s;
        }

        unsigned long long colr[15];
        #pragma unroll
        for (int p = 0; p < 15; ++p)
            colr[p] = (unsigned long long)s_col32[(p * 2 + 0) * 64 + lane]
                    | ((unsigned long long)s_col32[(p * 2 + 1) * 64 + lane] << 32);

        // Suppressor-only greedy scan (proven R15): iterate only alive&rowany boxes.
        #pragma unroll
        for (int w = 0; w < 5; ++w) {
            if (w * 64 < nv) {
                unsigned long long outs = 0ull;
                #pragma unroll
                for (int s2 = w; s2 < 5; ++s2) outs |= colr[pairidx(w, s2)];
                #pragma unroll
                for (int d = 1; d < 64; d <<= 1) outs |= __shfl_xor(outs, d);   // rowany

                unsigned long long alive = __ballot((keep >> w) & 1u);
                unsigned long long todo  = alive & outs;
                while (todo) {
                    const int tb = (int)__builtin_ctzll(todo);
                    const unsigned long long supww =
                        __ballot((unsigned)((colr[pairidx(w, w)] >> tb) & 1ull));
                    alive &= ~supww;
                    todo  &= ~supww;
                    todo  &= ~(1ull << tb);
                    #pragma unroll
                    for (int s2 = w + 1; s2 < 5; ++s2) {
                        const unsigned bit = (unsigned)((colr[pairidx(w, s2)] >> tb) & 1ull);
                        keep &= ~(bit << s2);
                    }
                }
                const unsigned kbit = (unsigned)((alive >> lane) & 1ull);
                keep = (keep & ~(1u << w)) | (kbit << w);
            }
        }

        // ballot prefix-popcount output compaction (verbatim R12-R15)
        int total = 0;
        #pragma unroll
        for (int s = 0; s < 5; ++s) {
            const unsigned long long m = __ballot((keep >> s) & 1u);
            const bool mine = (keep >> s) & 1u;
            const int p = total + (int)__popcll(m & ((1ull << lane) - 1ull));
            if (mine && p < KK) {
                float* dst = wsBoxes + (((size_t)(b * NFG + ci)) * KK + p) * 4;
                *(float4*)dst = bx[s];
            }
            total += (int)__popcll(m);
        }
        if (lane == 0) wsCount[b * NFG + ci] = (unsigned)total;
    }

    // ================= grid-wide barrier; then blocks 0-7 select =================
    cg::this_grid().sync();

    if (blk < 8 && wave == 0) {
        // block blk has b == blk (ci == 0); select image b. (register-only, proven R12-R15)
        const int cnt = (lane < NFG) ? (int)wsCount[b * NFG + lane] : 0;
        const int cap = (cnt < KK) ? cnt : KK;
        int scap = cap, sfull = cnt;
        #pragma unroll
        for (int d = 1; d < 32; d <<= 1) {
            const int u1 = __shfl_up(scap, d);
            const int u2 = __shfl_up(sfull, d);
            if (lane >= d) { scap += u1; sfull += u2; }
        }
        const int fullT = __builtin_amdgcn_readlane(sfull, NFG - 1);
        const int n = (fullT < KK) ? fullT : KK;

        int cc = 0, pe = 0;
        #pragma unroll 4
        for (int q = 0; q < NFG; ++q) {
            const int piq = __builtin_amdgcn_readlane(scap, q);
            if (piq <= lane) { cc = q + 1; pe = piq; }
        }
        if (lane < KK) {
            float o0 = 0.f, o1 = 0.f, o2 = 0.f, o3 = 0.f, o4 = 0.f;
            if (lane < n) {
                const float* bp = wsBoxes + (((size_t)(b * NFG + cc)) * KK + (lane - pe)) * 4;
                o0 = bp[0]; o1 = bp[1]; o2 = bp[2]; o3 = bp[3];
                o4 = (float)(cc + 1);
            }
            float* ob = out + (size_t)b * (KK * 5) + lane * 5;
            ob[0] = o0; ob[1] = o1; ob[2] = o2; ob[3] = o3; ob[4] = o4;
        }
        if (lane == 0) out[(size_t)B * KK * 5 + b] = (float)n;
    }
}

extern "C" void kernel_launch(void* const* d_in, const int* in_sizes, int n_in,
                              void* d_out, int out_size, void* d_ws, size_t ws_size,
                              hipStream_t stream)
{
    const float* cls_prob  = (const float*)d_in[0];
    const float* rois      = (const float*)d_in[1];
    const float* bbox_pred = (const float*)d_in[2];
    const float* im_info   = (const float*)d_in[3];
    const float* thr       = (const float*)d_in[4];
    int B = in_sizes[3] / 3;   // im_info is [B,3]

    float*    wsBoxes = (float*)d_ws;                                       // B*NFG*KK*4 floats
    unsigned* wsCount = (unsigned*)((char*)d_ws + (size_t)B * NFG * KK * 4 * sizeof(float));
    float*    outp    = (float*)d_out;

    void* args[] = { (void*)&cls_prob, (void*)&rois, (void*)&bbox_pred,
                     (void*)&im_info, (void*)&thr,
                     (void*)&wsBoxes, (void*)&wsCount, (void*)&outp, (void*)&B };
    hipLaunchCooperativeKernel((const void*)nms_coop_kernel,
                               dim3(B * NFG), dim3(THREADS), args, 0, stream);
}

// Round 18
// 30.096 us; speedup vs baseline: 2.0151x; 2.0151x over previous
//
#include <hip/hip_runtime.h>
#include <math.h>

#define RR      300   // rois per image
#define NCLS    21    // classes incl background
#define NFG     20    // foreground classes
#define KK      21    // output pad size (== num_classes)
#define THREADS 1024  // 16 waves
#define NWAVES  16

// Block FMA contraction: t = a*b rounded separately, then + c. (bit-exact vs ref, proven R1-R15)
__device__ __forceinline__ float madd_nofma(float a, float b, float c) {
    float t = a * b;
    asm volatile("" : "+v"(t));
    return t + c;
}

// Correctly-rounded float32 exp via double (bit-exact vs ref, proven R1-R15)
__device__ __forceinline__ float exp_acc(float x) {
    return (float)exp((double)x);
}

// pair index for upper-triangle (q <= s2): (0,0..4),(1,1..4),(2,2..4),(3,3..4),(4,4)
__host__ __device__ constexpr int pairidx(int q, int s2) {
    return q * 5 - (q * (q - 1)) / 2 + (s2 - q);
}

// Exact replacement for RN32(inter/U) > 0.3f (U > 0):  (double)inter > M*(double)U,
// M = midpoint(0.3f, nextafterf(0.3f)); products exact in double. (proven R9-R15)
#define M_THR ((((double)0.30000001192092896) + ((double)0.30000004172325134)) * 0.5)

// One block (16 waves) per (image, fg-class). Two-kernel structure (R12-R15, passing).
__global__ __launch_bounds__(THREADS)
void nms_per_class_kernel(const float* __restrict__ cls_prob,   // [B,RR,NCLS]
                          const float* __restrict__ rois,       // [B,RR,5]
                          const float* __restrict__ bbox_pred,  // [B,RR,4*NCLS]
                          const float* __restrict__ im_info,    // [B,3]
                          const float* __restrict__ thr,        // [NCLS]
                          float* __restrict__ wsBoxes,          // [B,NFG,KK,4]
                          int*   __restrict__ wsCount)          // [B,NFG]
{
    const int blk  = blockIdx.x;
    const int b    = blk & 7;                // XCD-local image (B == 8)
    const int ci   = blk >> 3;               // fg class index 0..19
    const int c    = ci + 1;                 // skip background
    const int lane = threadIdx.x & 63;
    const int wave = threadIdx.x >> 6;

    __shared__ unsigned long long s_keys[RR];     // sortable key per ORIGINAL roi index
    __shared__ unsigned long long s_ckeys[320];   // compacted VALID keys (lim-bounded reads)
    __shared__ unsigned short     s_vpre[RR];     // #valid j < r (exclusive prefix)
    __shared__ unsigned short     s_pr[RR];       // partial rank (upper j-half), waves 5-9
    __shared__ float4 s_boxS[320];                // decoded boxes in SORTED order (+pad)
    __shared__ float  s_areaS[320];
    __shared__ unsigned s_col32[15 * 2 * 64];     // suppression column halves (pre-zeroed)
    __shared__ int s_nv;

    const float imH = im_info[b * 3 + 0];
    const float imW = im_info[b * 3 + 1];
    const float t   = thr[c];

    // ================= Phase A (wave 15) — overlaps decode on waves 0-4 =================
    if (wave == 15) {
        int base = 0;
        #pragma unroll
        for (int s = 0; s < 5; ++s) {
            const int r  = s * 64 + lane;
            const int rc = (r < RR) ? r : 0;
            const float sc = cls_prob[(b * RR + rc) * NCLS + c];
            const bool valid = (r < RR) && (sc > t);
            const unsigned u = valid ? (__float_as_uint(sc) | 0x80000000u) : 0u;
            const unsigned long long key = ((unsigned long long)u << 32) | (unsigned)(~r);
            const unsigned long long m = __ballot(valid);
            const int pre = base + (int)__popcll(m & ((1ull << lane) - 1ull));
            if (r < RR) { s_keys[r] = key; s_vpre[r] = (unsigned short)pre; }
            if (valid)  { s_ckeys[pre] = key; }
            base += (int)__popcll(m);
        }
        if (lane == 0) s_nv = base;
    } else if (wave >= 5) {
        // waves 5-14: zero suppression columns + LDS pads
        for (int idx = (wave - 5) * 64 + lane; idx < 15 * 2 * 64; idx += 10 * 64)
            s_col32[idx] = 0u;
        const int p = (wave - 5) * 64 + lane;
        if (p < 20) { s_boxS[RR + p] = make_float4(0.f, 0.f, 0.f, 0.f); s_areaS[RR + p] = 0.f; }
    }

    // waves 0-4: decode own roi (independent of rank)
    const int  k   = (wave < 5 ? wave : wave - 5) * 60 + lane;  // own roi for wave-pairs
    const bool own = (lane < 60);
    const int  kc  = own ? k : 0;                 // clamped (in-bounds for ALL lanes)
    float dbx1 = 0.f, dby1 = 0.f, dbx2 = 0.f, dby2 = 0.f, darea = 0.f;
    if (wave < 5) {
        const float* rp = &rois[(size_t)(b * RR + kc) * 5];
        const float x1 = rp[1], y1 = rp[2], x2 = rp[3], y2 = rp[4];
        const float4 dv = *(const float4*)&bbox_pred[((size_t)(b * RR + kc) * NCLS + c) * 4];
        // decode (verbatim expressions, proven bit-exact R1-R15)
        float w  = x2 - x1 + 1.0f;
        float h  = y2 - y1 + 1.0f;
        float cx = x1 + 0.5f * w;
        float cy = y1 + 0.5f * h;
        float dx = dv.x * 0.1f;
        float dy = dv.y * 0.1f;
        float dw = dv.z * 0.2f;
        float dh = dv.w * 0.2f;
        float pcx = madd_nofma(dx, w, cx);
        float pcy = madd_nofma(dy, h, cy);
        float pw  = exp_acc(dw) * w;
        float ph  = exp_acc(dh) * h;
        dbx1 = fminf(fmaxf(pcx - 0.5f * pw, 0.0f), imW - 1.0f);
        dby1 = fminf(fmaxf(pcy - 0.5f * ph, 0.0f), imH - 1.0f);
        dbx2 = fminf(fmaxf(pcx + 0.5f * pw, 0.0f), imW - 1.0f);
        dby2 = fminf(fmaxf(pcy + 0.5f * ph, 0.0f), imH - 1.0f);
        darea = (dbx2 - dbx1 + 1.0f) * (dby2 - dby1 + 1.0f);
    }
    __syncthreads();

    const int nv  = s_nv;
    const int nvh = nv >> 1;                      // j-range split point

    // ================= Phase B1: split rank (waves 0-9) =================
    // FULL-EXEC rule (R10/R11 lesson): key loads + readlane loop run at full exec;
    // loads pinned via asm; only stores guarded.
    int   prA = 0;                                // this wave's partial rank
    unsigned long long mykey = 0ull;
    if (wave < 10) {
        unsigned klo[5], khi[5];
        #pragma unroll
        for (int s = 0; s < 5; ++s) {
            const unsigned long long kk2 = s_ckeys[s * 64 + lane];
            klo[s] = (unsigned)kk2;
            khi[s] = (unsigned)(kk2 >> 32);
            asm volatile("" : "+v"(klo[s]), "+v"(khi[s]));   // pin at full exec
        }
        mykey = s_keys[kc];
        const int jlo = (wave >= 5) ? nvh : 0;    // wave-uniform
        const int jhi = (wave >= 5) ? nv  : nvh;
        #pragma unroll
        for (int s = 0; s < 5; ++s) {
            int st = jlo - s * 64; st = (st < 0) ? 0 : st;
            int en = jhi - s * 64; en = (en < 0) ? 0 : ((en > 64) ? 64 : en);
            for (int jj = st; jj < en; ++jj) {
                const unsigned lo = (unsigned)__builtin_amdgcn_readlane((int)klo[s], jj);
                const unsigned hi = (unsigned)__builtin_amdgcn_readlane((int)khi[s], jj);
                const unsigned long long kj = ((unsigned long long)hi << 32) | lo;
                prA += (kj > mykey) ? 1 : 0;
            }
        }
        if (wave >= 5 && own) s_pr[k] = (unsigned short)prA;
    }
    __syncthreads();

    // ================= Phase B2: combine + store (waves 0-4) =================
    if (wave < 5) {
        const int lrank = prA + (int)s_pr[kc];
        const int irank = nv + (k - (int)s_vpre[kc]);         // invalid-roi closed form
        const int rank  = (mykey >> 63) ? lrank : irank;      // branchless select
        if (own) {
            s_boxS[rank]  = make_float4(dbx1, dby1, dbx2, dby2);
            s_areaS[rank] = darea;
        }
    }
    __syncthreads();

    // ================= Phase C: build (all 16 waves, alive tiles only) =================
    const int nb = (nv + 63) >> 6;                 // alive j/i blocks
    const int np = nb * (nb + 1) / 2;              // alive upper-triangle tiles
    const int ntasks = np * 2;                     // 32-row half-tiles
    const double Md = M_THR;
    for (int task = wave; task < ntasks; task += NWAVES) {
        const int pa = task >> 1, h = task & 1;
        int S2 = 0, a = pa;
        while (a > S2) { a -= (S2 + 1); ++S2; }    // S2-major: (0,0),(0,1),(1,1),(0,2)...
        const int Q = a;
        const int qbase = Q * 64;
        int rows = nv - qbase;
        rows = (rows > 64) ? 64 : rows;
        const int rcap = RR - qbase;
        rows = (rows > rcap) ? rcap : rows;
        const int i0 = h * 32;
        int i1 = i0 + 32; i1 = (i1 > rows) ? rows : i1;
        if (i0 >= i1) continue;
        const int jg = S2 * 64 + lane;
        const bool jv = jg < nv;
        const float4 bj = s_boxS[jg];
        const float  aj = s_areaS[jg];
        unsigned colw = 0u;
        #pragma unroll 4
        for (int ii = i0; ii < i1; ++ii) {
            const float4 bi = s_boxS[qbase + ii];   // broadcast (conflict-free)
            const float  ai = s_areaS[qbase + ii];
            float xx1 = fmaxf(bi.x, bj.x);
            float yy1 = fmaxf(bi.y, bj.y);
            float xx2 = fminf(bi.z, bj.z);
            float yy2 = fminf(bi.w, bj.w);
            float inter = fmaxf(xx2 - xx1 + 1.0f, 0.0f) * fmaxf(yy2 - yy1 + 1.0f, 0.0f);
            float uni = (ai + aj) - inter;
            bool sup = ((double)inter > Md * (double)uni);
            bool gtr = (S2 > Q) || (lane > ii);
            colw |= (sup && gtr && jv) ? (1u << (ii - i0)) : 0u;
        }
        s_col32[(pairidx(Q, S2) * 2 + h) * 64 + lane] = colw;
    }
    __syncthreads();
    if (wave != 0) return;

    // ================= Phase D: wave 0 scan + compaction =================
    float4 bx[5];
    unsigned keep = 0;
    #pragma unroll
    for (int s = 0; s < 5; ++s) {
        bx[s] = s_boxS[s * 64 + lane];
        keep |= (((s * 64 + lane) < nv) ? 1u : 0u) << s;
    }

    unsigned long long colr[15];
    #pragma unroll
    for (int p = 0; p < 15; ++p)
        colr[p] = (unsigned long long)s_col32[(p * 2 + 0) * 64 + lane]
                | ((unsigned long long)s_col32[(p * 2 + 1) * 64 + lane] << 32);

    // Suppressor-only greedy scan (proven R15): iterate only alive&rowany boxes.
    #pragma unroll
    for (int w = 0; w < 5; ++w) {
        if (w * 64 < nv) {
            unsigned long long outs = 0ull;
            #pragma unroll
            for (int s2 = w; s2 < 5; ++s2) outs |= colr[pairidx(w, s2)];
            #pragma unroll
            for (int d = 1; d < 64; d <<= 1) outs |= __shfl_xor(outs, d);   // rowany (uniform)

            unsigned long long alive = __ballot((keep >> w) & 1u);
            unsigned long long todo  = alive & outs;
            while (todo) {
                const int tb = (int)__builtin_ctzll(todo);
                const unsigned long long supww =
                    __ballot((unsigned)((colr[pairidx(w, w)] >> tb) & 1ull));
                alive &= ~supww;
                todo  &= ~supww;
                todo  &= ~(1ull << tb);
                #pragma unroll
                for (int s2 = w + 1; s2 < 5; ++s2) {
                    const unsigned bit = (unsigned)((colr[pairidx(w, s2)] >> tb) & 1ull);
                    keep &= ~(bit << s2);
                }
            }
            const unsigned kbit = (unsigned)((alive >> lane) & 1ull);
            keep = (keep & ~(1u << w)) | (kbit << w);
        }
    }

    // ballot prefix-popcount output compaction (verbatim R12-R15)
    int total = 0;
    #pragma unroll
    for (int s = 0; s < 5; ++s) {
        const unsigned long long m = __ballot((keep >> s) & 1u);
        const bool mine = (keep >> s) & 1u;
        const int p = total + (int)__popcll(m & ((1ull << lane) - 1ull));
        if (mine && p < KK) {
            float* dst = wsBoxes + (((size_t)(b * NFG + ci)) * KK + p) * 4;
            *(float4*)dst = bx[s];
        }
        total += (int)__popcll(m);
    }
    if (lane == 0) wsCount[b * NFG + ci] = total;
}

// Per-image top-K select: one wave, register-only prefix scans (R12-R15, passing).
__global__ __launch_bounds__(64)
void select_topk_kernel(const float* __restrict__ wsBoxes,
                        const int*   __restrict__ wsCount,
                        float* __restrict__ out,   // [B,KK,5] then [B] counts
                        int B)
{
    const int b = blockIdx.x;
    const int lane = threadIdx.x;

    const int cnt = (lane < NFG) ? wsCount[b * NFG + lane] : 0;
    const int cap = (cnt < KK) ? cnt : KK;
    int scap = cap, sfull = cnt;
    #pragma unroll
    for (int d = 1; d < 32; d <<= 1) {
        const int u1 = __shfl_up(scap, d);
        const int u2 = __shfl_up(sfull, d);
        if (lane >= d) { scap += u1; sfull += u2; }
    }
    const int fullT = __builtin_amdgcn_readlane(sfull, NFG - 1);
    const int n = (fullT < KK) ? fullT : KK;

    // row = lane: class cc = (last q with incl_cap_prefix(q) <= row) + 1; pe = that prefix
    int cc = 0, pe = 0;
    #pragma unroll 4
    for (int q = 0; q < NFG; ++q) {
        const int piq = __builtin_amdgcn_readlane(scap, q);
        if (piq <= lane) { cc = q + 1; pe = piq; }
    }
    if (lane < KK) {
        float o0 = 0.f, o1 = 0.f, o2 = 0.f, o3 = 0.f, o4 = 0.f;
        if (lane < n) {
            const float* bp = wsBoxes + (((size_t)(b * NFG + cc)) * KK + (lane - pe)) * 4;
            o0 = bp[0]; o1 = bp[1]; o2 = bp[2]; o3 = bp[3];
            o4 = (float)(cc + 1);
        }
        float* ob = out + (size_t)b * (KK * 5) + lane * 5;
        ob[0] = o0; ob[1] = o1; ob[2] = o2; ob[3] = o3; ob[4] = o4;
    }
    if (lane == 0) out[(size_t)B * KK * 5 + b] = (float)n;
}

extern "C" void kernel_launch(void* const* d_in, const int* in_sizes, int n_in,
                              void* d_out, int out_size, void* d_ws, size_t ws_size,
                              hipStream_t stream)
{
    const float* cls_prob  = (const float*)d_in[0];
    const float* rois      = (const float*)d_in[1];
    const float* bbox_pred = (const float*)d_in[2];
    const float* im_info   = (const float*)d_in[3];
    const float* thr       = (const float*)d_in[4];
    const int B = in_sizes[3] / 3;   // im_info is [B,3]

    float* wsBoxes = (float*)d_ws;                                         // B*NFG*KK*4 floats
    int*   wsCount = (int*)((char*)d_ws + (size_t)B * NFG * KK * 4 * sizeof(float));

    nms_per_class_kernel<<<B * NFG, THREADS, 0, stream>>>(
        cls_prob, rois, bbox_pred, im_info, thr, wsBoxes, wsCount);
    select_topk_kernel<<<B, 64, 0, stream>>>(
        wsBoxes, wsCount, (float*)d_out, B);
}